// Round 1
// baseline (172.514 us; speedup 1.0000x reference)
//
#include <hip/hip_runtime.h>

#define S_DIV 14.0f
#define N_BATCH 4096
#define NCELL (4096 * 14 * 14)   // 802816

// ---------------------------------------------------------------------------
// Kernel 1: detect mask storage layout + zero the accumulators.
// flag: 0 = int32 (0/1), 1 = float32 (0.0/1.0), 2 = uint8 (numpy bool)
// Scans first 4096 words (16 KB) — in-bounds for every candidate layout
// (smallest possible buffer is 802816 bytes).
// ---------------------------------------------------------------------------
__global__ void detect_and_zero(const unsigned int* __restrict__ mask_words,
                                double* __restrict__ acc,
                                int* __restrict__ flag) {
    __shared__ int s_notInt, s_notFloat;
    const int tid = threadIdx.x;
    if (tid == 0) { s_notInt = 0; s_notFloat = 0; }
    __syncthreads();
    int notInt = 0, notFloat = 0;
    for (int i = tid; i < 4096; i += 256) {
        const unsigned int u = mask_words[i];
        if (u > 1u) notInt = 1;
        if (u != 0u && u != 0x3F800000u) notFloat = 1;
    }
    if (notInt)   atomicOr(&s_notInt, 1);
    if (notFloat) atomicOr(&s_notFloat, 1);
    __syncthreads();
    if (tid == 0) {
        *flag = (!s_notInt) ? 0 : ((!s_notFloat) ? 1 : 2);
        acc[0] = 0.0; acc[1] = 0.0; acc[2] = 0.0; acc[3] = 0.0;
    }
}

// ---------------------------------------------------------------------------
// Kernel 2: main loss computation, one thread per cell.
// acc layout: [0]=reg, [1]=conf, [2]=noobj, [3]=cls (un-normalized sums)
// ---------------------------------------------------------------------------
__device__ __forceinline__ float iou_xyxy(const float a0, const float a1,
                                          const float a2, const float a3,
                                          const float b0, const float b1,
                                          const float b2, const float b3) {
    const float ltx = fmaxf(a0, b0), lty = fmaxf(a1, b1);
    const float rbx = fminf(a2, b2), rby = fminf(a3, b3);
    const float wx = fmaxf(rbx - ltx, 0.0f), wy = fmaxf(rby - lty, 0.0f);
    const float inter = wx * wy;
    const float area_a = (a2 - a0) * (a3 - a1);
    const float area_b = (b2 - b0) * (b3 - b1);
    return inter / (area_a + area_b - inter);
}

__global__ __launch_bounds__(256) void yolo_loss_main(
    const float* __restrict__ pred,
    const float* __restrict__ tbox,
    const float* __restrict__ tcls,
    const void* __restrict__ maskp,
    const int* __restrict__ flagp,
    double* __restrict__ acc) {

    const int idx = blockIdx.x * blockDim.x + threadIdx.x;
    float reg = 0.0f, conf = 0.0f, noobj = 0.0f, cls = 0.0f;
    const int flag = *flagp;

    if (idx < NCELL) {
        bool m;
        if (flag == 0)      m = ((const int*)maskp)[idx] != 0;
        else if (flag == 1) m = ((const float*)maskp)[idx] != 0.0f;
        else                m = ((const unsigned char*)maskp)[idx] != 0;
        const float mf = m ? 1.0f : 0.0f;
        const float nf = 1.0f - mf;

        const float* p = pred + (size_t)idx * 30;
        float pr[30];
        #pragma unroll
        for (int i = 0; i < 30; ++i) pr[i] = p[i];

        const float4 tb = ((const float4*)tbox)[idx];
        const float* tc = tcls + (size_t)idx * 20;

        // class loss
        float c = 0.0f;
        #pragma unroll
        for (int i = 0; i < 20; ++i) {
            const float d = pr[10 + i] - tc[i];
            c += d * d;
        }
        cls = mf * c;

        // no-object loss
        noobj = nf * (pr[4] * pr[4] + pr[9] * pr[9]);

        // xywh -> xyxy (divisions kept IEEE to match reference)
        const float b1x0 = pr[0] / S_DIV - 0.5f * pr[2];
        const float b1y0 = pr[1] / S_DIV - 0.5f * pr[3];
        const float b1x1 = pr[0] / S_DIV + 0.5f * pr[2];
        const float b1y1 = pr[1] / S_DIV + 0.5f * pr[3];
        const float b2x0 = pr[5] / S_DIV - 0.5f * pr[7];
        const float b2y0 = pr[6] / S_DIV - 0.5f * pr[8];
        const float b2x1 = pr[5] / S_DIV + 0.5f * pr[7];
        const float b2y1 = pr[6] / S_DIV + 0.5f * pr[8];
        const float btx0 = tb.x / S_DIV - 0.5f * tb.z;
        const float bty0 = tb.y / S_DIV - 0.5f * tb.w;
        const float btx1 = tb.x / S_DIV + 0.5f * tb.z;
        const float bty1 = tb.y / S_DIV + 0.5f * tb.w;

        const float i1 = iou_xyxy(b1x0, b1y0, b1x1, b1y1, btx0, bty0, btx1, bty1);
        const float i2 = iou_xyxy(b2x0, b2y0, b2x1, b2y1, btx0, bty0, btx1, bty1);

        const bool take1 = i1 > i2;
        const float best_iou = take1 ? i1 : i2;
        const float bx = take1 ? pr[0] : pr[5];
        const float by = take1 ? pr[1] : pr[6];
        const float bw = take1 ? pr[2] : pr[7];
        const float bh = take1 ? pr[3] : pr[8];
        const float bc = take1 ? pr[4] : pr[9];

        const float dx = bx - tb.x;
        const float dy = by - tb.y;
        const float pw = m ? sqrtf(bw) : 1.0f;
        const float ph = m ? sqrtf(bh) : 1.0f;
        const float tw = m ? sqrtf(tb.z) : 1.0f;
        const float th = m ? sqrtf(tb.w) : 1.0f;
        reg = mf * (dx * dx + dy * dy)
            + mf * ((pw - tw) * (pw - tw) + (ph - th) * (ph - th));

        const float dc = bc - best_iou;
        conf = mf * dc * dc;
    }

    // wave reduction (64 lanes)
    #pragma unroll
    for (int off = 32; off > 0; off >>= 1) {
        reg   += __shfl_down(reg,   off);
        conf  += __shfl_down(conf,  off);
        noobj += __shfl_down(noobj, off);
        cls   += __shfl_down(cls,   off);
    }

    __shared__ float s[4][4];
    const int lane = threadIdx.x & 63;
    const int wid  = threadIdx.x >> 6;
    if (lane == 0) {
        s[0][wid] = reg; s[1][wid] = conf; s[2][wid] = noobj; s[3][wid] = cls;
    }
    __syncthreads();
    if (threadIdx.x == 0) {
        float r = 0.0f, cf = 0.0f, no = 0.0f, cl = 0.0f;
        #pragma unroll
        for (int w = 0; w < 4; ++w) {
            r += s[0][w]; cf += s[1][w]; no += s[2][w]; cl += s[3][w];
        }
        atomicAdd(&acc[0], (double)r);
        atomicAdd(&acc[1], (double)cf);
        atomicAdd(&acc[2], (double)no);
        atomicAdd(&acc[3], (double)cl);
    }
}

// ---------------------------------------------------------------------------
// Kernel 3: finalize — normalize and combine into the 5 outputs.
// ---------------------------------------------------------------------------
__global__ void yolo_finalize(const double* __restrict__ acc,
                              float* __restrict__ out) {
    if (threadIdx.x == 0 && blockIdx.x == 0) {
        const float invN = 1.0f / (float)N_BATCH;
        const float reg   = (float)acc[0] * invN;
        const float conf  = (float)acc[1] * invN;
        const float noobj = (float)acc[2] * invN;
        const float cls   = (float)acc[3] * invN;
        out[0] = 5.0f * reg + conf + 0.5f * noobj + cls;
        out[1] = reg;
        out[2] = conf;
        out[3] = noobj;
        out[4] = cls;
    }
}

extern "C" void kernel_launch(void* const* d_in, const int* in_sizes, int n_in,
                              void* d_out, int out_size, void* d_ws, size_t ws_size,
                              hipStream_t stream) {
    const float* pred = (const float*)d_in[0];
    const float* tbox = (const float*)d_in[1];
    const float* tcls = (const float*)d_in[2];
    const void*  mask = (const void*)d_in[3];
    float* out = (float*)d_out;

    double* acc = (double*)d_ws;                    // 4 doubles
    int* flag   = (int*)((char*)d_ws + 32);         // 1 int

    detect_and_zero<<<1, 256, 0, stream>>>((const unsigned int*)mask, acc, flag);
    yolo_loss_main<<<NCELL / 256, 256, 0, stream>>>(pred, tbox, tcls, mask, flag, acc);
    yolo_finalize<<<1, 64, 0, stream>>>(acc, out);
}